// Round 8
// baseline (191.466 us; speedup 1.0000x reference)
//
#include <hip/hip_runtime.h>
#include <hip/hip_bf16.h>

// Problem constants (B,H,L,D = 2,16,2048,64)
#define BB 2
#define HH 16
#define LL 2048
#define DD 64
constexpr int BH = BB * HH;   // 32 heads
constexpr int NT = LL / 64;   // 32 tiles of 64

typedef __attribute__((ext_vector_type(8))) short bf16x8;  // 8 bf16 (4 VGPR)
typedef __attribute__((ext_vector_type(4))) float f32x4;   // 4 f32

typedef unsigned short u16;
typedef unsigned int u32;

__device__ __forceinline__ u16 f2bf(float x) {
    __bf16 b = (__bf16)x;          // RNE convert
    u16 u; __builtin_memcpy(&u, &b, 2);
    return u;
}
__device__ __forceinline__ float bf2f(u16 u) {
    union { u32 i; float f; } c; c.i = ((u32)u) << 16; return c.f;
}

// async global->LDS, 16B per lane; lds dest = wave-uniform base + lane*16
__device__ __forceinline__ void gll16(const void* gptr, void* ldsptr) {
    __builtin_amdgcn_global_load_lds(
        (const u32 __attribute__((address_space(1)))*)gptr,
        (u32 __attribute__((address_space(3)))*)ldsptr, 16, 0, 0);
}

// fragment read: one ds_read_b128 from a swizzled row-major [64][64] bf16 tile.
__device__ __forceinline__ bf16x8 ld_frag(const char* tile, int row, int kbyte) {
    return *(const bf16x8*)(tile + row * 128 + (kbyte ^ ((row & 7) << 4)));
}

// ---------------------------------------------------------------------------
// fmap2: hi = bf16(relu(x @ W)) per head, pre-swizzled 64x64 tiles.
// TSUM: per-tile per-dim column sums of the ROUNDED bf16 values.
// VPREP: additionally transpose one V tile (fp32 [c][e] -> bf16 swizzled [e][c]).
// ---------------------------------------------------------------------------
template<bool TSUM, bool VPREP>
__global__ __launch_bounds__(256) void fmap2_kernel(
    const float* __restrict__ x, const float* __restrict__ W,
    u16* __restrict__ ghi, float* __restrict__ tsum,
    const float* __restrict__ v, u16* __restrict__ vt)
{
    __shared__ float sXT[64][64];
    __shared__ float sW[64][64];
    int bx = blockIdx.x;
    int bh = bx / NT, rb = bx % NT;
    int h = bh % HH;
    const float* xp = x + (size_t)bh * LL * DD + (size_t)rb * 64 * DD;
    const float* wp = W + (size_t)h * DD * DD;

    int tid = threadIdx.x;
    {
        int r = tid >> 2, c0 = (tid & 3) * 16;
        for (int u = 0; u < 16; u += 4) {
            float4 t = *(const float4*)(xp + r * DD + c0 + u);
            sXT[c0 + u + 0][r] = t.x; sXT[c0 + u + 1][r] = t.y;
            sXT[c0 + u + 2][r] = t.z; sXT[c0 + u + 3][r] = t.w;
            *(float4*)(&sW[r][c0 + u]) = *(const float4*)(wp + r * DD + c0 + u);
        }
    }
    __syncthreads();

    int ty = tid >> 4, tx = tid & 15;
    float acc[4][4] = {};
    #pragma unroll 4
    for (int d = 0; d < 64; ++d) {
        float4 a = *(const float4*)(&sXT[d][ty * 4]);
        float4 b = *(const float4*)(&sW[d][tx * 4]);
        float av[4] = {a.x, a.y, a.z, a.w};
        float bv[4] = {b.x, b.y, b.z, b.w};
        #pragma unroll
        for (int j = 0; j < 4; ++j)
            #pragma unroll
            for (int i = 0; i < 4; ++i)
                acc[j][i] = fmaf(av[j], bv[i], acc[j][i]);
    }

    char* hib = (char*)ghi + (size_t)bx * 8192;
    float colsum[4] = {0.f, 0.f, 0.f, 0.f};
    #pragma unroll
    for (int j = 0; j < 4; ++j) {
        int rr = ty * 4 + j;
        ushort4 hv;
        hv.x = f2bf(fmaxf(acc[j][0], 0.f));
        hv.y = f2bf(fmaxf(acc[j][1], 0.f));
        hv.z = f2bf(fmaxf(acc[j][2], 0.f));
        hv.w = f2bf(fmaxf(acc[j][3], 0.f));
        int off = rr * 128 + ((tx * 8) ^ ((rr & 7) << 4));
        *(ushort4*)(hib + off) = hv;
        if constexpr (TSUM) {
            colsum[0] += bf2f(hv.x); colsum[1] += bf2f(hv.y);
            colsum[2] += bf2f(hv.z); colsum[3] += bf2f(hv.w);
        }
    }

    if constexpr (TSUM) {
        __syncthreads();           // safe to reuse sXT
        #pragma unroll
        for (int i = 0; i < 4; ++i)
            sXT[ty][tx * 4 + i] = colsum[i];
        __syncthreads();
        if (tid < 64) {
            float s = 0.f;
            #pragma unroll
            for (int y = 0; y < 16; ++y) s += sXT[y][tid];
            tsum[(size_t)bx * 64 + tid] = s;
        }
    }

    if constexpr (VPREP) {
        int c0 = (tid >> 4) * 4, e0 = (tid & 15) * 4;
        const float* vp = v + ((size_t)bh * LL + (size_t)rb * 64) * DD;
        float ld[4][4];
        #pragma unroll
        for (int j = 0; j < 4; ++j) {
            float4 f = *(const float4*)(vp + (size_t)(c0 + j) * DD + e0);
            ld[j][0] = f.x; ld[j][1] = f.y; ld[j][2] = f.z; ld[j][3] = f.w;
        }
        char* base = (char*)vt + (size_t)bx * 8192;
        #pragma unroll
        for (int i = 0; i < 4; ++i) {
            int e = e0 + i;
            ushort4 wv;
            wv.x = f2bf(ld[0][i]); wv.y = f2bf(ld[1][i]);
            wv.z = f2bf(ld[2][i]); wv.w = f2bf(ld[3][i]);
            *(ushort4*)(base + e * 128 + ((c0 * 2) ^ ((e & 7) << 4))) = wv;
        }
    }
}

// ---------------------------------------------------------------------------
// rowsum: rinv[bh][r] = 1 / (fq_r . cumsum(fk)_r). 1024 blocks, 4 waves each.
// ---------------------------------------------------------------------------
__global__ __launch_bounds__(256) void rowsum_kernel(
    const u16* __restrict__ khi, const u16* __restrict__ qhi,
    const float* __restrict__ tsum, float* __restrict__ rinv)
{
    __shared__ float wsum[4][64];
    int bx = blockIdx.x;
    int bh = bx >> 5, t = bx & 31;
    int w = threadIdx.x >> 6, d = threadIdx.x & 63;
    const size_t tb = ((size_t)bh * NT + t) * 4096;

    float fkv[16];
    float s = 0.f;
    #pragma unroll
    for (int i = 0; i < 16; ++i) {
        int r = w * 16 + i;
        size_t idx = tb + r * 64 + (d ^ ((r & 7) << 3));
        fkv[i] = bf2f(khi[idx]);
        s += fkv[i];
    }
    wsum[w][d] = s;
    __syncthreads();

    float cs = 0.f;
    for (int t2 = 0; t2 < t; ++t2)
        cs += tsum[((size_t)bh * NT + t2) * 64 + d];
    for (int w2 = 0; w2 < w; ++w2) cs += wsum[w2][d];

    #pragma unroll
    for (int i = 0; i < 16; ++i) {
        int r = w * 16 + i;
        size_t idx = tb + r * 64 + (d ^ ((r & 7) << 3));
        cs += fkv[i];
        float tt = bf2f(qhi[idx]) * cs;
        #pragma unroll
        for (int o = 1; o < 64; o <<= 1) tt += __shfl_xor(tt, o);
        if (d == 0) rinv[(size_t)bh * LL + t * 64 + r] = 1.0f / tt;
    }
}

// ---------------------------------------------------------------------------
// attn6: store-pipelined version.
//  - wave-private sS (each wave owns 16 rows): NO mid-tile barrier.
//  - loop-end: counted s_waitcnt vmcnt(8|4) + raw s_barrier (stores never
//    drained in-loop; >= 1 iteration of ack slack).
//  - zero-fill tiles interleaved one-per-main-iteration (global queue across
//    both halves; 33 mains >= 31 zeros).
// Grid = 512 blocks = (head, pair p): row-blocks p and 31-p -> uniform work.
// ---------------------------------------------------------------------------
__global__ __launch_bounds__(256, 4) void attn6_kernel(
    const u16* __restrict__ qhi, const u16* __restrict__ khi,
    const u16* __restrict__ vt, const float* __restrict__ rinvg,
    float* __restrict__ outO, float* __restrict__ outA)
{
    __shared__ __align__(16) char lds[40960];
    char* sS = lds + 32768;

    int bx = blockIdx.x;
    int bh = bx & 31;        // head -> XCD = bh&7 (K/VT L2 reuse)
    int p = bx >> 5;         // pair index 0..15

    int tid = threadIdx.x;
    int w = tid >> 6, l = tid & 63;
    int l15 = l & 15, lq = l >> 4;
    int o = tid * 16, wb = w << 10;

    const f32x4 zvec = {0.f, 0.f, 0.f, 0.f};
    int z = 0;                       // zero tiles consumed (global, 0..31)
    const int z_half0 = 31 - p;      // zero tiles belonging to half0

    for (int half = 0; half < 2; ++half) {
        int rblk = half ? (31 - p) : p;
        int brow = rblk * 64;

        // ---- prologue: stage Q -> buf1 area, tile0 K/VT -> buf0 ----
        {
            const char* qT = (const char*)qhi + ((size_t)bh * NT + rblk) * 8192;
            gll16(qT + o,        lds + 16384 + wb);
            gll16(qT + o + 4096, lds + 16384 + wb + 4096);

            const char* kT = (const char*)khi + (size_t)bh * NT * 8192;
            const char* vT = (const char*)vt  + (size_t)bh * NT * 8192;
            gll16(kT + o,        lds + wb);
            gll16(kT + o + 4096, lds + wb + 4096);
            gll16(vT + o,        lds + 8192 + wb);
            gll16(vT + o + 4096, lds + 8192 + wb + 4096);
        }
        float ri = rinvg[(size_t)bh * LL + brow + w * 16 + l15];
        __builtin_amdgcn_sched_barrier(0);
        asm volatile("s_waitcnt vmcnt(0)" ::: "memory");
        __builtin_amdgcn_sched_barrier(0);
        __builtin_amdgcn_s_barrier();
        __builtin_amdgcn_sched_barrier(0);

        // Q fragments to registers; must COMPLETE before buf1 reuse (iter 0)
        int qrow = w * 16 + l15;
        bf16x8 bq[2];
        #pragma unroll
        for (int ks = 0; ks < 2; ++ks)
            bq[ks] = ld_frag(lds + 16384, qrow, lq * 16 + ks * 64);
        __builtin_amdgcn_sched_barrier(0);
        asm volatile("s_waitcnt lgkmcnt(0)" ::: "memory");
        __builtin_amdgcn_sched_barrier(0);
        __builtin_amdgcn_s_barrier();
        __builtin_amdgcn_sched_barrier(0);

        f32x4 acc2[4];
        #pragma unroll
        for (int eb = 0; eb < 4; ++eb) acc2[eb] = zvec;

        for (int ct = 0; ct <= rblk; ++ct) {
            char* cur = lds + (ct & 1) * 16384;
            bool willload = (ct < rblk);

            if (willload) {   // prefetch next tile FIRST (oldest in vmcnt queue)
                char* nxt = lds + ((ct + 1) & 1) * 16384;
                const char* kT = (const char*)khi + ((size_t)bh * NT + ct + 1) * 8192;
                const char* vT = (const char*)vt  + ((size_t)bh * NT + ct + 1) * 8192;
                gll16(kT + o,        nxt + wb);
                gll16(kT + o + 4096, nxt + wb + 4096);
                gll16(vT + o,        nxt + 8192 + wb);
                gll16(vT + o + 4096, nxt + 8192 + wb + 4096);
            }
            __builtin_amdgcn_sched_barrier(0);   // loads stay before stores

            // QK^T: S^T quadrants (single bf16 pass)
            f32x4 sa[4];
            #pragma unroll
            for (int cb = 0; cb < 4; ++cb) sa[cb] = zvec;
            #pragma unroll
            for (int ks = 0; ks < 2; ++ks) {
                #pragma unroll
                for (int cb = 0; cb < 4; ++cb) {
                    bf16x8 ah = ld_frag(cur, cb * 16 + l15, lq * 16 + ks * 64);
                    sa[cb] = __builtin_amdgcn_mfma_f32_16x16x32_bf16(ah, bq[ks], sa[cb], 0, 0, 0);
                }
            }

            bool diag = (ct == rblk);
            int srow = w * 16 + l15;
            #pragma unroll
            for (int cb = 0; cb < 4; ++cb) {
                if (diag) {
                    #pragma unroll
                    for (int rg = 0; rg < 4; ++rg)
                        if (cb * 16 + lq * 4 + rg > srow) sa[cb][rg] = 0.f;
                }
                sa[cb] *= ri;
                ushort4 pv;
                pv.x = f2bf(sa[cb][0]); pv.y = f2bf(sa[cb][1]);
                pv.z = f2bf(sa[cb][2]); pv.w = f2bf(sa[cb][3]);
                int soff = srow * 128 + ((cb * 32 + lq * 8) ^ ((srow & 7) << 4));
                *(ushort4*)(sS + soff) = pv;
            }

            // wave-private full-line attn store: wave w stores sS rows [16w,16w+16)
            {
                int bcol = ct * 64;
                float* atile = outA + ((size_t)bh * LL + brow) * LL + bcol;
                #pragma unroll
                for (int u = 0; u < 4; ++u) {
                    int r = w * 16 + u * 4 + lq;
                    ushort4 pv = *(const ushort4*)(sS + r * 128 + ((l15 * 8) ^ ((r & 7) << 4)));
                    f32x4 o4 = { bf2f(pv.x), bf2f(pv.y), bf2f(pv.z), bf2f(pv.w) };
                    __builtin_nontemporal_store(o4, (f32x4*)(atile + (size_t)r * LL + l15 * 4));
                }
            }

            // PV: out^T += V^T @ S^T (own sS rows only)
            bf16x8 pf[2];
            #pragma unroll
            for (int ks = 0; ks < 2; ++ks)
                pf[ks] = ld_frag(sS, srow, lq * 16 + ks * 64);
            #pragma unroll
            for (int ks = 0; ks < 2; ++ks) {
                #pragma unroll
                for (int eb = 0; eb < 4; ++eb) {
                    bf16x8 av = ld_frag(cur + 8192, eb * 16 + l15, lq * 16 + ks * 64);
                    acc2[eb] = __builtin_amdgcn_mfma_f32_16x16x32_bf16(av, pf[ks], acc2[eb], 0, 0, 0);
                }
            }

            // interleaved zero-fill tile (overlaps the store stream with compute)
            bool had_zero = (z < 31);
            if (had_zero) {
                int zbrow, zcol;
                if (z < z_half0) { zbrow = p * 64;        zcol = (p + 1 + z) * 64; }
                else             { zbrow = (31 - p) * 64; zcol = (32 - p + (z - z_half0)) * 64; }
                ++z;
                #pragma unroll
                for (int u = 0; u < 4; ++u) {
                    int idx = tid + u * 256;
                    int r = idx >> 4, c4 = idx & 15;
                    __builtin_nontemporal_store(zvec,
                        (f32x4*)(outA + ((size_t)bh * LL + zbrow + r) * LL + zcol + c4 * 4));
                }
            }

            // loop-end: counted wait (prefetch loads only; stores stay in flight)
            __builtin_amdgcn_sched_barrier(0);
            if (willload) {
                if (had_zero) asm volatile("s_waitcnt vmcnt(8)" ::: "memory");
                else          asm volatile("s_waitcnt vmcnt(4)" ::: "memory");
            }
            __builtin_amdgcn_sched_barrier(0);
            __builtin_amdgcn_s_barrier();
            __builtin_amdgcn_sched_barrier(0);
        }

        // out write (from out^T accumulators)
        float* oo = outO + ((size_t)bh * LL + brow + w * 16 + l15) * DD;
        #pragma unroll
        for (int eb = 0; eb < 4; ++eb) {
            float4 o4 = { acc2[eb][0], acc2[eb][1], acc2[eb][2], acc2[eb][3] };
            *(float4*)(oo + eb * 16 + lq * 4) = o4;
        }
    }
}

// ---------------------------------------------------------------------------
extern "C" void kernel_launch(void* const* d_in, const int* in_sizes, int n_in,
                              void* d_out, int out_size, void* d_ws, size_t ws_size,
                              hipStream_t stream)
{
    (void)in_sizes; (void)n_in; (void)out_size; (void)ws_size;
    const float* q  = (const float*)d_in[0];
    const float* k  = (const float*)d_in[1];
    const float* v  = (const float*)d_in[2];
    const float* Wq = (const float*)d_in[3];
    const float* Wk = (const float*)d_in[4];

    float* out  = (float*)d_out;                       // [B,H,L,D]
    float* attn = out + (size_t)BB * HH * LL * DD;     // [B,H,L,L]

    const size_t TILE_HW = (size_t)BH * NT * 4096;     // halfwords per bf16 array
    u16* QHI = (u16*)d_ws;
    u16* KHI = QHI + TILE_HW;
    u16* VT  = KHI + TILE_HW;
    float* RINV = (float*)(VT + TILE_HW);              // [BH, L]
    float* TSUM = RINV + (size_t)BH * LL;              // [BH, NT, 64]

    // NOTE reference swap: fq uses fm_k_weight, fk uses fm_q_weight.
    fmap2_kernel<false, true><<<BH * NT, 256, 0, stream>>>(q, Wk, QHI, nullptr, v, VT);
    fmap2_kernel<true, false><<<BH * NT, 256, 0, stream>>>(k, Wq, KHI, TSUM, nullptr, nullptr);
    rowsum_kernel<<<BH * NT, 256, 0, stream>>>(KHI, QHI, TSUM, RINV);
    attn6_kernel<<<BH * 16, 256, 0, stream>>>(QHI, KHI, VT, RINV, out, attn);
}

// Round 9
// 179.867 us; speedup vs baseline: 1.0645x; 1.0645x over previous
//
#include <hip/hip_runtime.h>
#include <hip/hip_bf16.h>

// Problem constants (B,H,L,D = 2,16,2048,64)
#define BB 2
#define HH 16
#define LL 2048
#define DD 64
constexpr int BH = BB * HH;   // 32 heads
constexpr int NT = LL / 64;   // 32 tiles of 64

typedef __attribute__((ext_vector_type(8))) short bf16x8;  // 8 bf16 (4 VGPR)
typedef __attribute__((ext_vector_type(4))) float f32x4;   // 4 f32

typedef unsigned short u16;
typedef unsigned int u32;

__device__ __forceinline__ u16 f2bf(float x) {
    __bf16 b = (__bf16)x;          // RNE convert
    u16 u; __builtin_memcpy(&u, &b, 2);
    return u;
}
__device__ __forceinline__ float bf2f(u16 u) {
    union { u32 i; float f; } c; c.i = ((u32)u) << 16; return c.f;
}

// async global->LDS, 16B per lane; lds dest = wave-uniform base + lane*16
__device__ __forceinline__ void gll16(const void* gptr, void* ldsptr) {
    __builtin_amdgcn_global_load_lds(
        (const u32 __attribute__((address_space(1)))*)gptr,
        (u32 __attribute__((address_space(3)))*)ldsptr, 16, 0, 0);
}

// fragment read: one ds_read_b128 from a swizzled row-major [64][64] bf16 tile.
__device__ __forceinline__ bf16x8 ld_frag(const char* tile, int row, int kbyte) {
    return *(const bf16x8*)(tile + row * 128 + (kbyte ^ ((row & 7) << 4)));
}

// ---------------------------------------------------------------------------
// fmap2: hi = bf16(relu(x @ W)) per head, pre-swizzled 64x64 tiles.
// TSUM: per-tile per-dim column sums of the ROUNDED bf16 values.
// VPREP: additionally transpose one V tile (fp32 [c][e] -> bf16 swizzled [e][c]).
// ---------------------------------------------------------------------------
template<bool TSUM, bool VPREP>
__global__ __launch_bounds__(256) void fmap2_kernel(
    const float* __restrict__ x, const float* __restrict__ W,
    u16* __restrict__ ghi, float* __restrict__ tsum,
    const float* __restrict__ v, u16* __restrict__ vt)
{
    __shared__ float sXT[64][64];
    __shared__ float sW[64][64];
    int bx = blockIdx.x;
    int bh = bx / NT, rb = bx % NT;
    int h = bh % HH;
    const float* xp = x + (size_t)bh * LL * DD + (size_t)rb * 64 * DD;
    const float* wp = W + (size_t)h * DD * DD;

    int tid = threadIdx.x;
    {
        int r = tid >> 2, c0 = (tid & 3) * 16;
        for (int u = 0; u < 16; u += 4) {
            float4 t = *(const float4*)(xp + r * DD + c0 + u);
            sXT[c0 + u + 0][r] = t.x; sXT[c0 + u + 1][r] = t.y;
            sXT[c0 + u + 2][r] = t.z; sXT[c0 + u + 3][r] = t.w;
            *(float4*)(&sW[r][c0 + u]) = *(const float4*)(wp + r * DD + c0 + u);
        }
    }
    __syncthreads();

    int ty = tid >> 4, tx = tid & 15;
    float acc[4][4] = {};
    #pragma unroll 4
    for (int d = 0; d < 64; ++d) {
        float4 a = *(const float4*)(&sXT[d][ty * 4]);
        float4 b = *(const float4*)(&sW[d][tx * 4]);
        float av[4] = {a.x, a.y, a.z, a.w};
        float bv[4] = {b.x, b.y, b.z, b.w};
        #pragma unroll
        for (int j = 0; j < 4; ++j)
            #pragma unroll
            for (int i = 0; i < 4; ++i)
                acc[j][i] = fmaf(av[j], bv[i], acc[j][i]);
    }

    char* hib = (char*)ghi + (size_t)bx * 8192;
    float colsum[4] = {0.f, 0.f, 0.f, 0.f};
    #pragma unroll
    for (int j = 0; j < 4; ++j) {
        int rr = ty * 4 + j;
        ushort4 hv;
        hv.x = f2bf(fmaxf(acc[j][0], 0.f));
        hv.y = f2bf(fmaxf(acc[j][1], 0.f));
        hv.z = f2bf(fmaxf(acc[j][2], 0.f));
        hv.w = f2bf(fmaxf(acc[j][3], 0.f));
        int off = rr * 128 + ((tx * 8) ^ ((rr & 7) << 4));
        *(ushort4*)(hib + off) = hv;
        if constexpr (TSUM) {
            colsum[0] += bf2f(hv.x); colsum[1] += bf2f(hv.y);
            colsum[2] += bf2f(hv.z); colsum[3] += bf2f(hv.w);
        }
    }

    if constexpr (TSUM) {
        __syncthreads();           // safe to reuse sXT
        #pragma unroll
        for (int i = 0; i < 4; ++i)
            sXT[ty][tx * 4 + i] = colsum[i];
        __syncthreads();
        if (tid < 64) {
            float s = 0.f;
            #pragma unroll
            for (int y = 0; y < 16; ++y) s += sXT[y][tid];
            tsum[(size_t)bx * 64 + tid] = s;
        }
    }

    if constexpr (VPREP) {
        int c0 = (tid >> 4) * 4, e0 = (tid & 15) * 4;
        const float* vp = v + ((size_t)bh * LL + (size_t)rb * 64) * DD;
        float ld[4][4];
        #pragma unroll
        for (int j = 0; j < 4; ++j) {
            float4 f = *(const float4*)(vp + (size_t)(c0 + j) * DD + e0);
            ld[j][0] = f.x; ld[j][1] = f.y; ld[j][2] = f.z; ld[j][3] = f.w;
        }
        char* base = (char*)vt + (size_t)bx * 8192;
        #pragma unroll
        for (int i = 0; i < 4; ++i) {
            int e = e0 + i;
            ushort4 wv;
            wv.x = f2bf(ld[0][i]); wv.y = f2bf(ld[1][i]);
            wv.z = f2bf(ld[2][i]); wv.w = f2bf(ld[3][i]);
            *(ushort4*)(base + e * 128 + ((c0 * 2) ^ ((e & 7) << 4))) = wv;
        }
    }
}

// ---------------------------------------------------------------------------
// rowsum: rinv[bh][r] = 1 / (fq_r . cumsum(fk)_r). 1024 blocks, 4 waves each.
// ---------------------------------------------------------------------------
__global__ __launch_bounds__(256) void rowsum_kernel(
    const u16* __restrict__ khi, const u16* __restrict__ qhi,
    const float* __restrict__ tsum, float* __restrict__ rinv)
{
    __shared__ float wsum[4][64];
    int bx = blockIdx.x;
    int bh = bx >> 5, t = bx & 31;
    int w = threadIdx.x >> 6, d = threadIdx.x & 63;
    const size_t tb = ((size_t)bh * NT + t) * 4096;

    float fkv[16];
    float s = 0.f;
    #pragma unroll
    for (int i = 0; i < 16; ++i) {
        int r = w * 16 + i;
        size_t idx = tb + r * 64 + (d ^ ((r & 7) << 3));
        fkv[i] = bf2f(khi[idx]);
        s += fkv[i];
    }
    wsum[w][d] = s;
    __syncthreads();

    float cs = 0.f;
    for (int t2 = 0; t2 < t; ++t2)
        cs += tsum[((size_t)bh * NT + t2) * 64 + d];
    for (int w2 = 0; w2 < w; ++w2) cs += wsum[w2][d];

    #pragma unroll
    for (int i = 0; i < 16; ++i) {
        int r = w * 16 + i;
        size_t idx = tb + r * 64 + (d ^ ((r & 7) << 3));
        cs += fkv[i];
        float tt = bf2f(qhi[idx]) * cs;
        #pragma unroll
        for (int o = 1; o < 64; o <<= 1) tt += __shfl_xor(tt, o);
        if (d == 0) rinv[(size_t)bh * LL + t * 64 + r] = 1.0f / tt;
    }
}

// ---------------------------------------------------------------------------
// attn7: batched-store version. Round-5 skeleton (dbuf K/VT, per-tile
// __syncthreads), but S tiles accumulate in 4 wave-private bf16 LDS slots
// (32KB) and flush once per 4-tile group as PLAIN (non-NT) stores with 1KB
// contiguous runs per instruction. Zero tiles unify into the same path.
// Every block writes its full 64x2048 stripe left-to-right.
// Grid = 1024 blocks = (rblk, head). LDS 64KB -> 2 blocks/CU.
// ---------------------------------------------------------------------------
__global__ __launch_bounds__(256, 2) void attn7_kernel(
    const u16* __restrict__ qhi, const u16* __restrict__ khi,
    const u16* __restrict__ vt, const float* __restrict__ rinvg,
    float* __restrict__ outO, float* __restrict__ outA)
{
    __shared__ __align__(16) char lds[65536];
    char* sS = lds + 32768;           // 4 slots x 8KB (bf16 64x64 swizzled)

    int bx = blockIdx.x;
    int bh = bx & 31;                 // consecutive blocks: different heads
    int rblk = bx >> 5;
    int brow = rblk * 64;

    int tid = threadIdx.x;
    int w = tid >> 6, l = tid & 63;
    int l15 = l & 15, lq = l >> 4;
    int o = tid * 16, wb = w << 10;

    const f32x4 zvec = {0.f, 0.f, 0.f, 0.f};

    // ---- prologue: stage Q -> sS area, tile0 K/VT -> buf0 ----
    {
        const char* qT = (const char*)qhi + ((size_t)bh * NT + rblk) * 8192;
        gll16(qT + o,        sS + wb);
        gll16(qT + o + 4096, sS + wb + 4096);

        const char* kT = (const char*)khi + (size_t)bh * NT * 8192;
        const char* vT = (const char*)vt  + (size_t)bh * NT * 8192;
        gll16(kT + o,        lds + wb);
        gll16(kT + o + 4096, lds + wb + 4096);
        gll16(vT + o,        lds + 8192 + wb);
        gll16(vT + o + 4096, lds + 8192 + wb + 4096);
    }
    float ri = rinvg[(size_t)bh * LL + brow + w * 16 + l15];
    asm volatile("s_waitcnt vmcnt(0)" ::: "memory");
    __syncthreads();

    // Q fragments to registers (wave-private rows; sS slot0 reused later by
    // the same wave only, lgkm ordering suffices)
    int qrow = w * 16 + l15;
    bf16x8 bq[2];
    #pragma unroll
    for (int ks = 0; ks < 2; ++ks)
        bq[ks] = ld_frag(sS, qrow, lq * 16 + ks * 64);

    f32x4 acc2[4];
    #pragma unroll
    for (int eb = 0; eb < 4; ++eb) acc2[eb] = zvec;

    int srow = w * 16 + l15;

    for (int g = 0; g < 8; ++g) {
        #pragma unroll
        for (int j = 0; j < 4; ++j) {
            int ct = g * 4 + j;
            char* slot = sS + j * 8192;

            if (ct <= rblk) {
                char* cur = lds + (ct & 1) * 16384;

                if (ct < rblk) {   // prefetch next tile into other buffer
                    char* nxt = lds + ((ct + 1) & 1) * 16384;
                    const char* kT = (const char*)khi + ((size_t)bh * NT + ct + 1) * 8192;
                    const char* vT = (const char*)vt  + ((size_t)bh * NT + ct + 1) * 8192;
                    gll16(kT + o,        nxt + wb);
                    gll16(kT + o + 4096, nxt + wb + 4096);
                    gll16(vT + o,        nxt + 8192 + wb);
                    gll16(vT + o + 4096, nxt + 8192 + wb + 4096);
                }

                // QK^T: S^T quadrants (single bf16 pass)
                f32x4 sa[4];
                #pragma unroll
                for (int cb = 0; cb < 4; ++cb) sa[cb] = zvec;
                #pragma unroll
                for (int ks = 0; ks < 2; ++ks) {
                    #pragma unroll
                    for (int cb = 0; cb < 4; ++cb) {
                        bf16x8 ah = ld_frag(cur, cb * 16 + l15, lq * 16 + ks * 64);
                        sa[cb] = __builtin_amdgcn_mfma_f32_16x16x32_bf16(ah, bq[ks], sa[cb], 0, 0, 0);
                    }
                }

                bool diag = (ct == rblk);
                #pragma unroll
                for (int cb = 0; cb < 4; ++cb) {
                    if (diag) {
                        #pragma unroll
                        for (int rg = 0; rg < 4; ++rg)
                            if (cb * 16 + lq * 4 + rg > srow) sa[cb][rg] = 0.f;
                    }
                    sa[cb] *= ri;
                    ushort4 pv;
                    pv.x = f2bf(sa[cb][0]); pv.y = f2bf(sa[cb][1]);
                    pv.z = f2bf(sa[cb][2]); pv.w = f2bf(sa[cb][3]);
                    int soff = srow * 128 + ((cb * 32 + lq * 8) ^ ((srow & 7) << 4));
                    *(ushort4*)(slot + soff) = pv;
                }

                // PV: out^T += V^T @ S^T (wave-private sS rows)
                bf16x8 pf[2];
                #pragma unroll
                for (int ks = 0; ks < 2; ++ks)
                    pf[ks] = ld_frag(slot, srow, lq * 16 + ks * 64);
                #pragma unroll
                for (int ks = 0; ks < 2; ++ks) {
                    #pragma unroll
                    for (int eb = 0; eb < 4; ++eb) {
                        bf16x8 av = ld_frag(cur + 8192, eb * 16 + l15, lq * 16 + ks * 64);
                        acc2[eb] = __builtin_amdgcn_mfma_f32_16x16x32_bf16(av, pf[ks], acc2[eb], 0, 0, 0);
                    }
                }

                asm volatile("s_waitcnt vmcnt(0)" ::: "memory");
                __syncthreads();   // dbuf handoff (prefetch complete)
            } else {
                // zero this slot's wave-private rows [16w,16w+16): 32B/lane
                *(f32x4*)(slot + w * 2048 + l * 32)      = zvec;
                *(f32x4*)(slot + w * 2048 + l * 32 + 16) = zvec;
            }
        }

        // ---- group store: 1KB-contiguous plain stores ----
        // wave w stores its own rows [16w,16w+16); lane l covers cols l*4..l*4+3
        // of this group's 256-col stripe (source tile = l>>4, col = (l&15)*4).
        {
            float* abase = outA + ((size_t)bh * LL + brow) * LL + g * 256;
            const char* src = sS + (l >> 4) * 8192;
            #pragma unroll
            for (int u = 0; u < 16; ++u) {
                int r = w * 16 + u;
                ushort4 pv = *(const ushort4*)(src + r * 128 + (((l15) * 8) ^ ((r & 7) << 4)));
                f32x4 o4 = { bf2f(pv.x), bf2f(pv.y), bf2f(pv.z), bf2f(pv.w) };
                *(f32x4*)(abase + (size_t)r * LL + l * 4) = o4;
            }
        }
    }

    // out write (from out^T accumulators)
    float* oo = outO + ((size_t)bh * LL + brow + w * 16 + l15) * DD;
    #pragma unroll
    for (int eb = 0; eb < 4; ++eb) {
        float4 o4 = { acc2[eb][0], acc2[eb][1], acc2[eb][2], acc2[eb][3] };
        *(float4*)(oo + eb * 16 + lq * 4) = o4;
    }
}

// ---------------------------------------------------------------------------
extern "C" void kernel_launch(void* const* d_in, const int* in_sizes, int n_in,
                              void* d_out, int out_size, void* d_ws, size_t ws_size,
                              hipStream_t stream)
{
    (void)in_sizes; (void)n_in; (void)out_size; (void)ws_size;
    const float* q  = (const float*)d_in[0];
    const float* k  = (const float*)d_in[1];
    const float* v  = (const float*)d_in[2];
    const float* Wq = (const float*)d_in[3];
    const float* Wk = (const float*)d_in[4];

    float* out  = (float*)d_out;                       // [B,H,L,D]
    float* attn = out + (size_t)BB * HH * LL * DD;     // [B,H,L,L]

    const size_t TILE_HW = (size_t)BH * NT * 4096;     // halfwords per bf16 array
    u16* QHI = (u16*)d_ws;
    u16* KHI = QHI + TILE_HW;
    u16* VT  = KHI + TILE_HW;
    float* RINV = (float*)(VT + TILE_HW);              // [BH, L]
    float* TSUM = RINV + (size_t)BH * LL;              // [BH, NT, 64]

    // NOTE reference swap: fq uses fm_k_weight, fk uses fm_q_weight.
    fmap2_kernel<false, true><<<BH * NT, 256, 0, stream>>>(q, Wk, QHI, nullptr, v, VT);
    fmap2_kernel<true, false><<<BH * NT, 256, 0, stream>>>(k, Wq, KHI, TSUM, nullptr, nullptr);
    rowsum_kernel<<<BH * NT, 256, 0, stream>>>(KHI, QHI, TSUM, RINV);
    attn7_kernel<<<BH * NT, 256, 0, stream>>>(QHI, KHI, VT, RINV, out, attn);
}

// Round 10
// 175.115 us; speedup vs baseline: 1.0934x; 1.0271x over previous
//
#include <hip/hip_runtime.h>
#include <hip/hip_bf16.h>

// Problem constants (B,H,L,D = 2,16,2048,64)
#define BB 2
#define HH 16
#define LL 2048
#define DD 64
constexpr int BH = BB * HH;   // 32 heads
constexpr int NT = LL / 64;   // 32 tiles of 64

typedef __attribute__((ext_vector_type(8))) short bf16x8;  // 8 bf16 (4 VGPR)
typedef __attribute__((ext_vector_type(4))) float f32x4;   // 4 f32

typedef unsigned short u16;
typedef unsigned int u32;

__device__ __forceinline__ u16 f2bf(float x) {
    __bf16 b = (__bf16)x;          // RNE convert
    u16 u; __builtin_memcpy(&u, &b, 2);
    return u;
}
__device__ __forceinline__ float bf2f(u16 u) {
    union { u32 i; float f; } c; c.i = ((u32)u) << 16; return c.f;
}

// async global->LDS, 16B per lane; lds dest = wave-uniform base + lane*16
__device__ __forceinline__ void gll16(const void* gptr, void* ldsptr) {
    __builtin_amdgcn_global_load_lds(
        (const u32 __attribute__((address_space(1)))*)gptr,
        (u32 __attribute__((address_space(3)))*)ldsptr, 16, 0, 0);
}

// fragment read: one ds_read_b128 from a swizzled row-major [64][64] bf16 tile.
__device__ __forceinline__ bf16x8 ld_frag(const char* tile, int row, int kbyte) {
    return *(const bf16x8*)(tile + row * 128 + (kbyte ^ ((row & 7) << 4)));
}

// ---------------------------------------------------------------------------
// fmap2: hi = bf16(relu(x @ W)) per head, pre-swizzled 64x64 tiles.
// TSUM: per-tile per-dim column sums of the ROUNDED bf16 values.
// VPREP: additionally transpose one V tile (fp32 [c][e] -> bf16 swizzled [e][c]).
// ---------------------------------------------------------------------------
template<bool TSUM, bool VPREP>
__global__ __launch_bounds__(256) void fmap2_kernel(
    const float* __restrict__ x, const float* __restrict__ W,
    u16* __restrict__ ghi, float* __restrict__ tsum,
    const float* __restrict__ v, u16* __restrict__ vt)
{
    __shared__ float sXT[64][64];
    __shared__ float sW[64][64];
    int bx = blockIdx.x;
    int bh = bx / NT, rb = bx % NT;
    int h = bh % HH;
    const float* xp = x + (size_t)bh * LL * DD + (size_t)rb * 64 * DD;
    const float* wp = W + (size_t)h * DD * DD;

    int tid = threadIdx.x;
    {
        int r = tid >> 2, c0 = (tid & 3) * 16;
        for (int u = 0; u < 16; u += 4) {
            float4 t = *(const float4*)(xp + r * DD + c0 + u);
            sXT[c0 + u + 0][r] = t.x; sXT[c0 + u + 1][r] = t.y;
            sXT[c0 + u + 2][r] = t.z; sXT[c0 + u + 3][r] = t.w;
            *(float4*)(&sW[r][c0 + u]) = *(const float4*)(wp + r * DD + c0 + u);
        }
    }
    __syncthreads();

    int ty = tid >> 4, tx = tid & 15;
    float acc[4][4] = {};
    #pragma unroll 4
    for (int d = 0; d < 64; ++d) {
        float4 a = *(const float4*)(&sXT[d][ty * 4]);
        float4 b = *(const float4*)(&sW[d][tx * 4]);
        float av[4] = {a.x, a.y, a.z, a.w};
        float bv[4] = {b.x, b.y, b.z, b.w};
        #pragma unroll
        for (int j = 0; j < 4; ++j)
            #pragma unroll
            for (int i = 0; i < 4; ++i)
                acc[j][i] = fmaf(av[j], bv[i], acc[j][i]);
    }

    char* hib = (char*)ghi + (size_t)bx * 8192;
    float colsum[4] = {0.f, 0.f, 0.f, 0.f};
    #pragma unroll
    for (int j = 0; j < 4; ++j) {
        int rr = ty * 4 + j;
        ushort4 hv;
        hv.x = f2bf(fmaxf(acc[j][0], 0.f));
        hv.y = f2bf(fmaxf(acc[j][1], 0.f));
        hv.z = f2bf(fmaxf(acc[j][2], 0.f));
        hv.w = f2bf(fmaxf(acc[j][3], 0.f));
        int off = rr * 128 + ((tx * 8) ^ ((rr & 7) << 4));
        *(ushort4*)(hib + off) = hv;
        if constexpr (TSUM) {
            colsum[0] += bf2f(hv.x); colsum[1] += bf2f(hv.y);
            colsum[2] += bf2f(hv.z); colsum[3] += bf2f(hv.w);
        }
    }

    if constexpr (TSUM) {
        __syncthreads();           // safe to reuse sXT
        #pragma unroll
        for (int i = 0; i < 4; ++i)
            sXT[ty][tx * 4 + i] = colsum[i];
        __syncthreads();
        if (tid < 64) {
            float s = 0.f;
            #pragma unroll
            for (int y = 0; y < 16; ++y) s += sXT[y][tid];
            tsum[(size_t)bx * 64 + tid] = s;
        }
    }

    if constexpr (VPREP) {
        int c0 = (tid >> 4) * 4, e0 = (tid & 15) * 4;
        const float* vp = v + ((size_t)bh * LL + (size_t)rb * 64) * DD;
        float ld[4][4];
        #pragma unroll
        for (int j = 0; j < 4; ++j) {
            float4 f = *(const float4*)(vp + (size_t)(c0 + j) * DD + e0);
            ld[j][0] = f.x; ld[j][1] = f.y; ld[j][2] = f.z; ld[j][3] = f.w;
        }
        char* base = (char*)vt + (size_t)bx * 8192;
        #pragma unroll
        for (int i = 0; i < 4; ++i) {
            int e = e0 + i;
            ushort4 wv;
            wv.x = f2bf(ld[0][i]); wv.y = f2bf(ld[1][i]);
            wv.z = f2bf(ld[2][i]); wv.w = f2bf(ld[3][i]);
            *(ushort4*)(base + e * 128 + ((c0 * 2) ^ ((e & 7) << 4))) = wv;
        }
    }
}

// ---------------------------------------------------------------------------
// rowsum: rinv[bh][r] = 1 / (fq_r . cumsum(fk)_r). 1024 blocks, 4 waves each.
// ---------------------------------------------------------------------------
__global__ __launch_bounds__(256) void rowsum_kernel(
    const u16* __restrict__ khi, const u16* __restrict__ qhi,
    const float* __restrict__ tsum, float* __restrict__ rinv)
{
    __shared__ float wsum[4][64];
    int bx = blockIdx.x;
    int bh = bx >> 5, t = bx & 31;
    int w = threadIdx.x >> 6, d = threadIdx.x & 63;
    const size_t tb = ((size_t)bh * NT + t) * 4096;

    float fkv[16];
    float s = 0.f;
    #pragma unroll
    for (int i = 0; i < 16; ++i) {
        int r = w * 16 + i;
        size_t idx = tb + r * 64 + (d ^ ((r & 7) << 3));
        fkv[i] = bf2f(khi[idx]);
        s += fkv[i];
    }
    wsum[w][d] = s;
    __syncthreads();

    float cs = 0.f;
    for (int t2 = 0; t2 < t; ++t2)
        cs += tsum[((size_t)bh * NT + t2) * 64 + d];
    for (int w2 = 0; w2 < w; ++w2) cs += wsum[w2][d];

    #pragma unroll
    for (int i = 0; i < 16; ++i) {
        int r = w * 16 + i;
        size_t idx = tb + r * 64 + (d ^ ((r & 7) << 3));
        cs += fkv[i];
        float tt = bf2f(qhi[idx]) * cs;
        #pragma unroll
        for (int o = 1; o < 64; o <<= 1) tt += __shfl_xor(tt, o);
        if (d == 0) rinv[(size_t)bh * LL + t * 64 + r] = 1.0f / tt;
    }
}

// ---------------------------------------------------------------------------
// attn8: round-5 skeleton (best, 169us) with exactly two changes:
//  (1) wave-private attn store (wave stores its own 16 sS rows; mid-tile
//      barrier deleted — same 256B/row coalescing).
//  (2) loop-end __syncthreads -> s_waitcnt vmcnt(4) lgkmcnt(0) + s_barrier:
//      the 4 newest vm-ops (this tile's attn stores) stay in flight; the
//      prefetch loads (older) are drained. Store acks get a full tile of
//      slack instead of being drained 33x per block.
// 40KB LDS -> 4 blocks/CU. Grid = 1024 = (swizzled rblk, head).
// ---------------------------------------------------------------------------
__global__ __launch_bounds__(256, 4) void attn8_kernel(
    const u16* __restrict__ qhi, const u16* __restrict__ khi,
    const u16* __restrict__ vt, const float* __restrict__ rinvg,
    float* __restrict__ outO, float* __restrict__ outA)
{
    __shared__ __align__(16) char lds[40960];
    char* sS = lds + 32768;

    int bx = blockIdx.x;
    // XCD-grouping: 4 consecutive heads per XCD; interleave long/short rblk
    int bh = (bx & 7) * 4 + (bx >> 8);
    int jj = (bx >> 3) & 31;
    int rblk = (jj & 1) ? (jj >> 1) : (31 - (jj >> 1));
    int brow = rblk * 64;

    int tid = threadIdx.x;
    int w = tid >> 6, l = tid & 63;
    int l15 = l & 15, lq = l >> 4;
    int o = tid * 16, wb = w << 10;

    // ---- prologue: stage Q -> buf1 area, tile0 K/VT -> buf0 ----
    {
        const char* qT = (const char*)qhi + ((size_t)bh * NT + rblk) * 8192;
        gll16(qT + o,        lds + 16384 + wb);
        gll16(qT + o + 4096, lds + 16384 + wb + 4096);

        const char* kT = (const char*)khi + (size_t)bh * NT * 8192;
        const char* vT = (const char*)vt  + (size_t)bh * NT * 8192;
        gll16(kT + o,        lds + wb);
        gll16(kT + o + 4096, lds + wb + 4096);
        gll16(vT + o,        lds + 8192 + wb);
        gll16(vT + o + 4096, lds + 8192 + wb + 4096);
    }
    float ri = rinvg[(size_t)bh * LL + brow + w * 16 + l15];
    asm volatile("s_waitcnt vmcnt(0)" ::: "memory");
    __syncthreads();

    // Q fragments to registers (must complete before buf1 reuse at ct=0 prefetch)
    int qrow = w * 16 + l15;
    bf16x8 bq[2];
    #pragma unroll
    for (int ks = 0; ks < 2; ++ks)
        bq[ks] = ld_frag(lds + 16384, qrow, lq * 16 + ks * 64);
    __syncthreads();   // lowers with lgkmcnt(0): bq reads retired in all waves

    f32x4 acc2[4];
    #pragma unroll
    for (int eb = 0; eb < 4; ++eb) acc2[eb] = (f32x4){0.f, 0.f, 0.f, 0.f};

    int srow = w * 16 + l15;

    for (int ct = 0; ct <= rblk; ++ct) {
        char* cur = lds + (ct & 1) * 16384;
        bool willload = (ct < rblk);

        if (willload) {   // prefetch next tile into the other buffer
            char* nxt = lds + ((ct + 1) & 1) * 16384;
            const char* kT = (const char*)khi + ((size_t)bh * NT + ct + 1) * 8192;
            const char* vT = (const char*)vt  + ((size_t)bh * NT + ct + 1) * 8192;
            gll16(kT + o,        nxt + wb);
            gll16(kT + o + 4096, nxt + wb + 4096);
            gll16(vT + o,        nxt + 8192 + wb);
            gll16(vT + o + 4096, nxt + 8192 + wb + 4096);
        }

        // QK^T: S^T quadrants (single bf16 pass)
        f32x4 sa[4];
        #pragma unroll
        for (int cb = 0; cb < 4; ++cb) sa[cb] = (f32x4){0.f, 0.f, 0.f, 0.f};
        #pragma unroll
        for (int ks = 0; ks < 2; ++ks) {
            #pragma unroll
            for (int cb = 0; cb < 4; ++cb) {
                bf16x8 ah = ld_frag(cur, cb * 16 + l15, lq * 16 + ks * 64);
                sa[cb] = __builtin_amdgcn_mfma_f32_16x16x32_bf16(ah, bq[ks], sa[cb], 0, 0, 0);
            }
        }

        bool diag = (ct == rblk);
        #pragma unroll
        for (int cb = 0; cb < 4; ++cb) {
            if (diag) {
                #pragma unroll
                for (int rg = 0; rg < 4; ++rg)
                    if (cb * 16 + lq * 4 + rg > srow) sa[cb][rg] = 0.f;
            }
            sa[cb] *= ri;
            ushort4 pv;
            pv.x = f2bf(sa[cb][0]); pv.y = f2bf(sa[cb][1]);
            pv.z = f2bf(sa[cb][2]); pv.w = f2bf(sa[cb][3]);
            int soff = srow * 128 + ((cb * 32 + lq * 8) ^ ((srow & 7) << 4));
            *(ushort4*)(sS + soff) = pv;
        }

        // wave-private full-line attn store: wave w stores sS rows [16w,16w+16)
        // (written by this wave only — no barrier needed; compiler inserts the
        // lgkm wait for the LDS dependency)
        {
            int bcol = ct * 64;
            float* atile = outA + ((size_t)bh * LL + brow) * LL + bcol;
            #pragma unroll
            for (int u = 0; u < 4; ++u) {
                int r = w * 16 + u * 4 + lq;
                ushort4 pv = *(const ushort4*)(sS + r * 128 + ((l15 * 8) ^ ((r & 7) << 4)));
                f32x4 o4 = { bf2f(pv.x), bf2f(pv.y), bf2f(pv.z), bf2f(pv.w) };
                __builtin_nontemporal_store(o4, (f32x4*)(atile + (size_t)r * LL + l15 * 4));
            }
        }

        // PV: out^T += V^T @ S^T (own sS rows only)
        bf16x8 pf[2];
        #pragma unroll
        for (int ks = 0; ks < 2; ++ks)
            pf[ks] = ld_frag(sS, srow, lq * 16 + ks * 64);
        #pragma unroll
        for (int ks = 0; ks < 2; ++ks) {
            #pragma unroll
            for (int eb = 0; eb < 4; ++eb) {
                bf16x8 av = ld_frag(cur + 8192, eb * 16 + l15, lq * 16 + ks * 64);
                acc2[eb] = __builtin_amdgcn_mfma_f32_16x16x32_bf16(av, pf[ks], acc2[eb], 0, 0, 0);
            }
        }

        // loop-end: counted wait — drain prefetch loads (older), leave this
        // tile's 4 attn stores in flight; then workgroup barrier for dbuf.
        if (willload) {
            asm volatile("s_waitcnt vmcnt(4) lgkmcnt(0)" ::: "memory");
        } else {
            asm volatile("s_waitcnt lgkmcnt(0)" ::: "memory");
        }
        __builtin_amdgcn_s_barrier();
    }

    // zero-fill strictly-above-diagonal attn tiles (full-line coalesced)
    f32x4 z = {0.f, 0.f, 0.f, 0.f};
    for (int ct2 = rblk + 1; ct2 < NT; ++ct2) {
        int bcol = ct2 * 64;
        #pragma unroll
        for (int u = 0; u < 4; ++u) {
            int idx = tid + u * 256;
            int r = idx >> 4, c4 = idx & 15;
            __builtin_nontemporal_store(z,
                (f32x4*)(outA + ((size_t)bh * LL + brow + r) * LL + bcol + c4 * 4));
        }
    }

    // out write (from out^T accumulators)
    float* oo = outO + ((size_t)bh * LL + brow + w * 16 + l15) * DD;
    #pragma unroll
    for (int eb = 0; eb < 4; ++eb) {
        float4 o4 = { acc2[eb][0], acc2[eb][1], acc2[eb][2], acc2[eb][3] };
        *(float4*)(oo + eb * 16 + lq * 4) = o4;
    }
}

// ---------------------------------------------------------------------------
extern "C" void kernel_launch(void* const* d_in, const int* in_sizes, int n_in,
                              void* d_out, int out_size, void* d_ws, size_t ws_size,
                              hipStream_t stream)
{
    (void)in_sizes; (void)n_in; (void)out_size; (void)ws_size;
    const float* q  = (const float*)d_in[0];
    const float* k  = (const float*)d_in[1];
    const float* v  = (const float*)d_in[2];
    const float* Wq = (const float*)d_in[3];
    const float* Wk = (const float*)d_in[4];

    float* out  = (float*)d_out;                       // [B,H,L,D]
    float* attn = out + (size_t)BB * HH * LL * DD;     // [B,H,L,L]

    const size_t TILE_HW = (size_t)BH * NT * 4096;     // halfwords per bf16 array
    u16* QHI = (u16*)d_ws;
    u16* KHI = QHI + TILE_HW;
    u16* VT  = KHI + TILE_HW;
    float* RINV = (float*)(VT + TILE_HW);              // [BH, L]
    float* TSUM = RINV + (size_t)BH * LL;              // [BH, NT, 64]

    // NOTE reference swap: fq uses fm_k_weight, fk uses fm_q_weight.
    fmap2_kernel<false, true><<<BH * NT, 256, 0, stream>>>(q, Wk, QHI, nullptr, v, VT);
    fmap2_kernel<true, false><<<BH * NT, 256, 0, stream>>>(k, Wq, KHI, TSUM, nullptr, nullptr);
    rowsum_kernel<<<BH * NT, 256, 0, stream>>>(KHI, QHI, TSUM, RINV);
    attn8_kernel<<<BH * NT, 256, 0, stream>>>(QHI, KHI, VT, RINV, out, attn);
}

// Round 11
// 162.749 us; speedup vs baseline: 1.1764x; 1.0760x over previous
//
#include <hip/hip_runtime.h>
#include <hip/hip_bf16.h>

// Problem constants (B,H,L,D = 2,16,2048,64)
#define BB 2
#define HH 16
#define LL 2048
#define DD 64
constexpr int BH = BB * HH;   // 32 heads
constexpr int NT = LL / 64;   // 32 tiles of 64

typedef __attribute__((ext_vector_type(8))) short bf16x8;  // 8 bf16 (4 VGPR)
typedef __attribute__((ext_vector_type(4))) float f32x4;   // 4 f32

typedef unsigned short u16;
typedef unsigned int u32;

__device__ __forceinline__ u16 f2bf(float x) {
    __bf16 b = (__bf16)x;          // RNE convert
    u16 u; __builtin_memcpy(&u, &b, 2);
    return u;
}
__device__ __forceinline__ float bf2f(u16 u) {
    union { u32 i; float f; } c; c.i = ((u32)u) << 16; return c.f;
}

// async global->LDS, 16B per lane; lds dest = wave-uniform base + lane*16
__device__ __forceinline__ void gll16(const void* gptr, void* ldsptr) {
    __builtin_amdgcn_global_load_lds(
        (const u32 __attribute__((address_space(1)))*)gptr,
        (u32 __attribute__((address_space(3)))*)ldsptr, 16, 0, 0);
}

// fragment read: one ds_read_b128 from a swizzled row-major [64][64] bf16 tile.
__device__ __forceinline__ bf16x8 ld_frag(const char* tile, int row, int kbyte) {
    return *(const bf16x8*)(tile + row * 128 + (kbyte ^ ((row & 7) << 4)));
}

// ---------------------------------------------------------------------------
// fmap: merged q/k feature-map kernel, grid = 2*BH*NT.
//  q-side (bx < BH*NT):  QHI = bf16(relu(q @ Wk)) + V-tile transpose (VPREP)
//  k-side (bx >= BH*NT): KHI = bf16(relu(k @ Wq)) + per-tile column sums TSUM
// Tiles pre-swizzled: byte off = r*128 + ((c*2) ^ ((r&7)<<4)).
// ---------------------------------------------------------------------------
__global__ __launch_bounds__(256) void fmap_kernel(
    const float* __restrict__ q, const float* __restrict__ k,
    const float* __restrict__ Wq, const float* __restrict__ Wk,
    u16* __restrict__ QHI, u16* __restrict__ KHI,
    float* __restrict__ tsum,
    const float* __restrict__ v, u16* __restrict__ vt)
{
    __shared__ float sXT[64][64];
    __shared__ float sW[64][64];
    int bx0 = blockIdx.x;
    bool isK = bx0 >= BH * NT;
    int bx = isK ? bx0 - BH * NT : bx0;
    const float* x = isK ? k : q;
    const float* W = isK ? Wq : Wk;      // NOTE reference swap: fq uses Wk, fk uses Wq
    u16* ghi = isK ? KHI : QHI;

    int bh = bx / NT, rb = bx % NT;
    int h = bh % HH;
    const float* xp = x + (size_t)bh * LL * DD + (size_t)rb * 64 * DD;
    const float* wp = W + (size_t)h * DD * DD;

    int tid = threadIdx.x;
    {
        int r = tid >> 2, c0 = (tid & 3) * 16;
        for (int u = 0; u < 16; u += 4) {
            float4 t = *(const float4*)(xp + r * DD + c0 + u);
            sXT[c0 + u + 0][r] = t.x; sXT[c0 + u + 1][r] = t.y;
            sXT[c0 + u + 2][r] = t.z; sXT[c0 + u + 3][r] = t.w;
            *(float4*)(&sW[r][c0 + u]) = *(const float4*)(wp + r * DD + c0 + u);
        }
    }
    __syncthreads();

    int ty = tid >> 4, tx = tid & 15;
    float acc[4][4] = {};
    #pragma unroll 4
    for (int d = 0; d < 64; ++d) {
        float4 a = *(const float4*)(&sXT[d][ty * 4]);
        float4 b = *(const float4*)(&sW[d][tx * 4]);
        float av[4] = {a.x, a.y, a.z, a.w};
        float bv[4] = {b.x, b.y, b.z, b.w};
        #pragma unroll
        for (int j = 0; j < 4; ++j)
            #pragma unroll
            for (int i = 0; i < 4; ++i)
                acc[j][i] = fmaf(av[j], bv[i], acc[j][i]);
    }

    char* hib = (char*)ghi + (size_t)bx * 8192;
    float colsum[4] = {0.f, 0.f, 0.f, 0.f};
    #pragma unroll
    for (int j = 0; j < 4; ++j) {
        int rr = ty * 4 + j;
        ushort4 hv;
        hv.x = f2bf(fmaxf(acc[j][0], 0.f));
        hv.y = f2bf(fmaxf(acc[j][1], 0.f));
        hv.z = f2bf(fmaxf(acc[j][2], 0.f));
        hv.w = f2bf(fmaxf(acc[j][3], 0.f));
        int off = rr * 128 + ((tx * 8) ^ ((rr & 7) << 4));
        *(ushort4*)(hib + off) = hv;
        if (isK) {
            colsum[0] += bf2f(hv.x); colsum[1] += bf2f(hv.y);
            colsum[2] += bf2f(hv.z); colsum[3] += bf2f(hv.w);
        }
    }

    if (isK) {
        __syncthreads();           // safe to reuse sXT (block-uniform branch)
        #pragma unroll
        for (int i = 0; i < 4; ++i)
            sXT[ty][tx * 4 + i] = colsum[i];
        __syncthreads();
        if (tid < 64) {
            float s = 0.f;
            #pragma unroll
            for (int y = 0; y < 16; ++y) s += sXT[y][tid];
            tsum[(size_t)bx * 64 + tid] = s;
        }
    } else {
        // VPREP: V fp32 [c][e] -> bf16 swizzled [e][c] tile
        int c0 = (tid >> 4) * 4, e0 = (tid & 15) * 4;
        const float* vp = v + ((size_t)bh * LL + (size_t)rb * 64) * DD;
        float ld[4][4];
        #pragma unroll
        for (int j = 0; j < 4; ++j) {
            float4 f = *(const float4*)(vp + (size_t)(c0 + j) * DD + e0);
            ld[j][0] = f.x; ld[j][1] = f.y; ld[j][2] = f.z; ld[j][3] = f.w;
        }
        char* base = (char*)vt + (size_t)bx * 8192;
        #pragma unroll
        for (int i = 0; i < 4; ++i) {
            int e = e0 + i;
            ushort4 wv;
            wv.x = f2bf(ld[0][i]); wv.y = f2bf(ld[1][i]);
            wv.z = f2bf(ld[2][i]); wv.w = f2bf(ld[3][i]);
            *(ushort4*)(base + e * 128 + ((c0 * 2) ^ ((e & 7) << 4))) = wv;
        }
    }
}

// ---------------------------------------------------------------------------
// attn9: round-5 structure (169us best) + inline rinv (rowsum kernel folded
// into the prologue; bit-identical summation order).
//  phase A: Q -> buf1, K_diag -> buf0[0,8K); compute bq + rinv
//           (wsum/sInv scratch in buf0[8K,9.25K), freed before phase B).
//  phase B: tile0 K/VT -> buf0; then the unmodified round-5 main loop.
// 40KB LDS -> 4 blocks/CU. Grid = 1024 = (swizzled rblk, head).
// ---------------------------------------------------------------------------
__global__ __launch_bounds__(256, 4) void attn9_kernel(
    const u16* __restrict__ qhi, const u16* __restrict__ khi,
    const u16* __restrict__ vt, const float* __restrict__ tsum,
    float* __restrict__ outO, float* __restrict__ outA)
{
    __shared__ __align__(16) char lds[40960];
    char* sS = lds + 32768;

    int bx = blockIdx.x;
    // XCD-grouping: 4 consecutive heads per XCD; interleave long/short rblk
    int bh = (bx & 7) * 4 + (bx >> 8);
    int jj = (bx >> 3) & 31;
    int rblk = (jj & 1) ? (jj >> 1) : (31 - (jj >> 1));
    int brow = rblk * 64;

    int tid = threadIdx.x;
    int w = tid >> 6, l = tid & 63;
    int l15 = l & 15, lq = l >> 4;
    int o = tid * 16, wb = w << 10;

    // ---- phase A: Q -> buf1, K_diag -> buf0[0,8K) ----
    {
        const char* qT  = (const char*)qhi + ((size_t)bh * NT + rblk) * 8192;
        const char* kdT = (const char*)khi + ((size_t)bh * NT + rblk) * 8192;
        gll16(qT + o,         lds + 16384 + wb);
        gll16(qT + o + 4096,  lds + 16384 + wb + 4096);
        gll16(kdT + o,        lds + wb);
        gll16(kdT + o + 4096, lds + wb + 4096);
    }
    asm volatile("s_waitcnt vmcnt(0)" ::: "memory");
    __syncthreads();

    // Q fragments to registers
    int qrow = w * 16 + l15;
    bf16x8 bq[2];
    #pragma unroll
    for (int ks = 0; ks < 2; ++ks)
        bq[ks] = ld_frag(lds + 16384, qrow, lq * 16 + ks * 64);

    // ---- inline rinv (rowsum logic on K_diag/Q tiles in LDS) ----
    // wave w owns rows [16w,16w+16); lane = dim d = l.
    float ri;
    {
        float* wsum = (float*)(lds + 8192);          // [4][64]
        float* sInv = (float*)(lds + 8192 + 1024);   // [64]
        float fkv[16];
        float s = 0.f;
        #pragma unroll
        for (int i = 0; i < 16; ++i) {
            int r = w * 16 + i;
            fkv[i] = bf2f(*(const u16*)(lds + r * 128 + ((l * 2) ^ ((r & 7) << 4))));
            s += fkv[i];
        }
        wsum[w * 64 + l] = s;
        __syncthreads();

        float cs = 0.f;
        for (int t2 = 0; t2 < rblk; ++t2)
            cs += tsum[((size_t)bh * NT + t2) * 64 + l];
        for (int w2 = 0; w2 < w; ++w2) cs += wsum[w2 * 64 + l];

        #pragma unroll
        for (int i = 0; i < 16; ++i) {
            int r = w * 16 + i;
            cs += fkv[i];
            float qv = bf2f(*(const u16*)(lds + 16384 + r * 128 + ((l * 2) ^ ((r & 7) << 4))));
            float tt = qv * cs;
            #pragma unroll
            for (int o2 = 1; o2 < 64; o2 <<= 1) tt += __shfl_xor(tt, o2);
            if (l == 0) sInv[w * 16 + i] = 1.0f / tt;
        }
        ri = sInv[w * 16 + l15];    // own wave's writes (in-wave lgkm ordering)
        __syncthreads();            // all waves done with K_diag/wsum/sInv
    }

    // ---- phase B: tile0 K/VT -> buf0 ----
    {
        const char* kT = (const char*)khi + (size_t)bh * NT * 8192;
        const char* vT = (const char*)vt  + (size_t)bh * NT * 8192;
        gll16(kT + o,        lds + wb);
        gll16(kT + o + 4096, lds + wb + 4096);
        gll16(vT + o,        lds + 8192 + wb);
        gll16(vT + o + 4096, lds + 8192 + wb + 4096);
    }
    asm volatile("s_waitcnt vmcnt(0)" ::: "memory");
    __syncthreads();

    f32x4 acc2[4];
    #pragma unroll
    for (int eb = 0; eb < 4; ++eb) acc2[eb] = (f32x4){0.f, 0.f, 0.f, 0.f};

    int srow = w * 16 + l15;

    for (int ct = 0; ct <= rblk; ++ct) {
        char* cur = lds + (ct & 1) * 16384;

        if (ct < rblk) {   // stage next tile into the other buffer
            char* nxt = lds + ((ct + 1) & 1) * 16384;
            const char* kT = (const char*)khi + ((size_t)bh * NT + ct + 1) * 8192;
            const char* vT = (const char*)vt  + ((size_t)bh * NT + ct + 1) * 8192;
            gll16(kT + o,        nxt + wb);
            gll16(kT + o + 4096, nxt + wb + 4096);
            gll16(vT + o,        nxt + 8192 + wb);
            gll16(vT + o + 4096, nxt + 8192 + wb + 4096);
        }

        // QK^T: S^T quadrants (single bf16 pass)
        f32x4 sa[4];
        #pragma unroll
        for (int cb = 0; cb < 4; ++cb) sa[cb] = (f32x4){0.f, 0.f, 0.f, 0.f};
        #pragma unroll
        for (int ks = 0; ks < 2; ++ks) {
            #pragma unroll
            for (int cb = 0; cb < 4; ++cb) {
                bf16x8 ah = ld_frag(cur, cb * 16 + l15, lq * 16 + ks * 64);
                sa[cb] = __builtin_amdgcn_mfma_f32_16x16x32_bf16(ah, bq[ks], sa[cb], 0, 0, 0);
            }
        }

        bool diag = (ct == rblk);
        #pragma unroll
        for (int cb = 0; cb < 4; ++cb) {
            if (diag) {
                #pragma unroll
                for (int rg = 0; rg < 4; ++rg)
                    if (cb * 16 + lq * 4 + rg > srow) sa[cb][rg] = 0.f;
            }
            sa[cb] *= ri;
            ushort4 pv;
            pv.x = f2bf(sa[cb][0]); pv.y = f2bf(sa[cb][1]);
            pv.z = f2bf(sa[cb][2]); pv.w = f2bf(sa[cb][3]);
            int soff = srow * 128 + ((cb * 32 + lq * 8) ^ ((srow & 7) << 4));
            *(ushort4*)(sS + soff) = pv;
        }

        // make sS visible to all waves WITHOUT draining vmcnt (stage in flight)
        asm volatile("s_waitcnt lgkmcnt(0)" ::: "memory");
        __builtin_amdgcn_sched_barrier(0);
        __builtin_amdgcn_s_barrier();
        __builtin_amdgcn_sched_barrier(0);

        // cooperative full-line attn store: 16 lanes cover one row's 256B
        {
            int bcol = ct * 64;
            float* atile = outA + ((size_t)bh * LL + brow) * LL + bcol;
            #pragma unroll
            for (int u = 0; u < 4; ++u) {
                int idx = tid + u * 256;
                int r = idx >> 4;
                int c = idx & 15;
                ushort4 pv = *(const ushort4*)(sS + r * 128 + ((c * 8) ^ ((r & 7) << 4)));
                f32x4 o4 = { bf2f(pv.x), bf2f(pv.y), bf2f(pv.z), bf2f(pv.w) };
                __builtin_nontemporal_store(o4, (f32x4*)(atile + (size_t)r * LL + c * 4));
            }
        }

        // PV: out^T += V^T @ S^T
        bf16x8 pf[2];
        #pragma unroll
        for (int ks = 0; ks < 2; ++ks)
            pf[ks] = ld_frag(sS, srow, lq * 16 + ks * 64);
        #pragma unroll
        for (int ks = 0; ks < 2; ++ks) {
            #pragma unroll
            for (int eb = 0; eb < 4; ++eb) {
                bf16x8 av = ld_frag(cur + 8192, eb * 16 + l15, lq * 16 + ks * 64);
                acc2[eb] = __builtin_amdgcn_mfma_f32_16x16x32_bf16(av, pf[ks], acc2[eb], 0, 0, 0);
            }
        }

        __syncthreads();   // drain (stage latency already hidden) + buffer handoff
    }

    // zero-fill strictly-above-diagonal attn tiles (full-line coalesced)
    f32x4 z = {0.f, 0.f, 0.f, 0.f};
    for (int ct2 = rblk + 1; ct2 < NT; ++ct2) {
        int bcol = ct2 * 64;
        #pragma unroll
        for (int u = 0; u < 4; ++u) {
            int idx = tid + u * 256;
            int r = idx >> 4, c4 = idx & 15;
            __builtin_nontemporal_store(z,
                (f32x4*)(outA + ((size_t)bh * LL + brow + r) * LL + bcol + c4 * 4));
        }
    }

    // out write (from out^T accumulators)
    float* oo = outO + ((size_t)bh * LL + brow + w * 16 + l15) * DD;
    #pragma unroll
    for (int eb = 0; eb < 4; ++eb) {
        float4 o4 = { acc2[eb][0], acc2[eb][1], acc2[eb][2], acc2[eb][3] };
        *(float4*)(oo + eb * 16 + lq * 4) = o4;
    }
}

// ---------------------------------------------------------------------------
extern "C" void kernel_launch(void* const* d_in, const int* in_sizes, int n_in,
                              void* d_out, int out_size, void* d_ws, size_t ws_size,
                              hipStream_t stream)
{
    (void)in_sizes; (void)n_in; (void)out_size; (void)ws_size;
    const float* q  = (const float*)d_in[0];
    const float* k  = (const float*)d_in[1];
    const float* v  = (const float*)d_in[2];
    const float* Wq = (const float*)d_in[3];
    const float* Wk = (const float*)d_in[4];

    float* out  = (float*)d_out;                       // [B,H,L,D]
    float* attn = out + (size_t)BB * HH * LL * DD;     // [B,H,L,L]

    const size_t TILE_HW = (size_t)BH * NT * 4096;     // halfwords per bf16 array
    u16* QHI = (u16*)d_ws;
    u16* KHI = QHI + TILE_HW;
    u16* VT  = KHI + TILE_HW;
    float* TSUM = (float*)(VT + TILE_HW);              // [BH, NT, 64]

    fmap_kernel<<<2 * BH * NT, 256, 0, stream>>>(q, k, Wq, Wk, QHI, KHI, TSUM, v, VT);
    attn9_kernel<<<BH * NT, 256, 0, stream>>>(QHI, KHI, VT, TSUM, out, attn);
}